// Round 2
// baseline (203.259 us; speedup 1.0000x reference)
//
#include <hip/hip_runtime.h>

#define H 1024
#define W 1024
#define NPIX (H*W)
#define BATCH 4
#define TX 64
#define TY 16
#define HX 66        // used columns of halo row
#define HXP 68       // padded row length (16B-aligned rows: 272B)
#define HY 18
#define NHALO (HY*HX)
#define NT 4         // tiles per block in pass1
#define SLOTS 32
// ws layout (floats): partials[b][i][slot], i in {qq0..2, kk0..2, qk[c*3+d]}, then M[b][9]
#define PART_FLOATS (BATCH*15*SLOTS)

__global__ __launch_bounds__(256) void pass1(
    const float* __restrict__ x, const float* __restrict__ fhigh,
    const float* __restrict__ qCw, const float* __restrict__ qdw,
    const float* __restrict__ kCw, const float* __restrict__ kdw,
    float* __restrict__ partials)
{
  __shared__ alignas(16) float qm[3][HY][HXP];
  __shared__ alignas(16) float km[3][HY][HXP];
  __shared__ float rb[4][15];

  const int tid = threadIdx.x;
  const int tileX = blockIdx.x;    // 0..15
  const int tileY4 = blockIdx.y;   // 0..15 (each covers NT tiles of TY rows)
  const int b = blockIdx.z;

  float wqc[9], wkc[9], wqd[27], wkd[27];
  #pragma unroll
  for (int i = 0; i < 9; i++) { wqc[i] = qCw[i]; wkc[i] = kCw[i]; }
  #pragma unroll
  for (int i = 0; i < 27; i++) { wqd[i] = qdw[i]; wkd[i] = kdw[i]; }

  const float* fb = fhigh + (size_t)b * 3 * NPIX;
  const float* xb = x + (size_t)b * NPIX * 3;

  const int tx = tid & 15;     // column group: pixels 4tx..4tx+3
  const int ty = tid >> 4;     // output row within tile, 0..15

  float acc[15];
  #pragma unroll
  for (int i = 0; i < 15; i++) acc[i] = 0.f;

  for (int t = 0; t < NT; ++t) {
    const int row0 = (tileY4 * NT + t) * TY;

    __syncthreads();   // protect previous tile's LDS reads
    for (int l = tid; l < NHALO; l += 256) {
      int hy = l / HX;
      int hx = l - hy * HX;
      int gy = row0 + hy - 1;
      int gx = tileX * TX + hx - 1;
      float f0 = 0.f, f1 = 0.f, f2 = 0.f, x0 = 0.f, x1 = 0.f, x2 = 0.f;
      if ((unsigned)gy < H && (unsigned)gx < W) {
        int p = gy * W + gx;
        f0 = fb[p]; f1 = fb[NPIX + p]; f2 = fb[2 * NPIX + p];
        const float* xp = xb + (size_t)p * 3;
        x0 = xp[0]; x1 = xp[1]; x2 = xp[2];
      }
      qm[0][hy][hx] = wqc[0]*f0 + wqc[1]*f1 + wqc[2]*f2;
      qm[1][hy][hx] = wqc[3]*f0 + wqc[4]*f1 + wqc[5]*f2;
      qm[2][hy][hx] = wqc[6]*f0 + wqc[7]*f1 + wqc[8]*f2;
      km[0][hy][hx] = wkc[0]*x0 + wkc[1]*x1 + wkc[2]*x2;
      km[1][hy][hx] = wkc[3]*x0 + wkc[4]*x1 + wkc[5]*x2;
      km[2][hy][hx] = wkc[6]*x0 + wkc[7]*x1 + wkc[8]*x2;
    }
    __syncthreads();

    // each thread: output row (row0+ty), 4 pixels starting at col tileX*TX+4tx
    float qv[3][4], kv[3][4];
    #pragma unroll
    for (int c = 0; c < 3; ++c) {
      #pragma unroll
      for (int i = 0; i < 4; ++i) { qv[c][i] = 0.f; kv[c][i] = 0.f; }
      #pragma unroll
      for (int dy = 0; dy < 3; ++dy) {
        const float4 a0 = *(const float4*)&qm[c][ty + dy][4 * tx];
        const float4 a1 = *(const float4*)&qm[c][ty + dy][4 * tx + 4];
        const float b0 = *(const float*)0 == *(const float*)0 ? 0.f : 0.f; (void)b0;
        const float q0 = wqd[c*9 + dy*3 + 0], q1 = wqd[c*9 + dy*3 + 1], q2 = wqd[c*9 + dy*3 + 2];
        qv[c][0] += q0*a0.x + q1*a0.y + q2*a0.z;
        qv[c][1] += q0*a0.y + q1*a0.z + q2*a0.w;
        qv[c][2] += q0*a0.z + q1*a0.w + q2*a1.x;
        qv[c][3] += q0*a0.w + q1*a1.x + q2*a1.y;
        const float4 c0v = *(const float4*)&km[c][ty + dy][4 * tx];
        const float4 c1v = *(const float4*)&km[c][ty + dy][4 * tx + 4];
        const float k0 = wkd[c*9 + dy*3 + 0], k1 = wkd[c*9 + dy*3 + 1], k2 = wkd[c*9 + dy*3 + 2];
        kv[c][0] += k0*c0v.x + k1*c0v.y + k2*c0v.z;
        kv[c][1] += k0*c0v.y + k1*c0v.z + k2*c0v.w;
        kv[c][2] += k0*c0v.z + k1*c0v.w + k2*c1v.x;
        kv[c][3] += k0*c0v.w + k1*c1v.x + k2*c1v.y;
      }
    }
    #pragma unroll
    for (int i = 0; i < 4; ++i) {
      #pragma unroll
      for (int c = 0; c < 3; ++c) { acc[c] += qv[c][i]*qv[c][i]; acc[3+c] += kv[c][i]*kv[c][i]; }
      #pragma unroll
      for (int c = 0; c < 3; ++c)
        #pragma unroll
        for (int d = 0; d < 3; ++d) acc[6 + c*3 + d] += qv[c][i]*kv[d][i];
    }
  }

  // wave64 shuffle reduce of 15 scalars
  #pragma unroll
  for (int off = 32; off >= 1; off >>= 1)
    #pragma unroll
    for (int i = 0; i < 15; i++)
      acc[i] += __shfl_down(acc[i], off, 64);

  const int wave = tid >> 6;
  if ((tid & 63) == 0) {
    #pragma unroll
    for (int i = 0; i < 15; i++) rb[wave][i] = acc[i];
  }
  __syncthreads();
  if (tid < 15) {
    float s = rb[0][tid] + rb[1][tid] + rb[2][tid] + rb[3][tid];
    int slot = (blockIdx.y * 16 + blockIdx.x) & (SLOTS - 1);
    atomicAdd(&partials[((b * 15 + tid) * SLOTS) + slot], s);
  }
}

__global__ void pass2(const float* __restrict__ partials,
                      const float* __restrict__ proj_w,
                      const float* __restrict__ temperature,
                      float* __restrict__ M)
{
  int b = threadIdx.x;
  if (b >= BATCH) return;
  float sums[15];
  #pragma unroll
  for (int i = 0; i < 15; i++) {
    float s = 0.f;
    for (int sl = 0; sl < SLOTS; sl++) s += partials[((b * 15 + i) * SLOTS) + sl];
    sums[i] = s;
  }
  float qn[3], kn[3];
  #pragma unroll
  for (int c = 0; c < 3; c++) { qn[c] = sqrtf(sums[c]); kn[c] = sqrtf(sums[3 + c]); }
  float t = temperature[0];
  float attn[3][3];
  #pragma unroll
  for (int c = 0; c < 3; c++) {
    float l[3];
    #pragma unroll
    for (int d = 0; d < 3; d++)
      l[d] = sums[6 + c*3 + d] / fmaxf(qn[c], 1e-12f) / fmaxf(kn[d], 1e-12f) * t;
    float m = fmaxf(l[0], fmaxf(l[1], l[2]));
    float e0 = expf(l[0] - m), e1 = expf(l[1] - m), e2 = expf(l[2] - m);
    float inv = 1.f / (e0 + e1 + e2);
    attn[c][0] = e0 * inv; attn[c][1] = e1 * inv; attn[c][2] = e2 * inv;
  }
  #pragma unroll
  for (int c = 0; c < 3; c++)
    #pragma unroll
    for (int d = 0; d < 3; d++)
      M[b * 9 + c * 3 + d] = proj_w[c*3+0]*attn[0][d]
                           + proj_w[c*3+1]*attn[1][d]
                           + proj_w[c*3+2]*attn[2][d];
}

__global__ __launch_bounds__(256) void pass3(
    const float* __restrict__ x,
    const float* __restrict__ kCw, const float* __restrict__ kdw,
    const float* __restrict__ M, const float* __restrict__ proj_b,
    float* __restrict__ out)
{
  __shared__ alignas(16) float km[3][HY][HXP];

  const int tid = threadIdx.x;
  const int tileX = blockIdx.x;   // 0..15
  const int tileY = blockIdx.y;   // 0..63
  const int b = blockIdx.z;

  float wkc[9], wkd[27];
  #pragma unroll
  for (int i = 0; i < 9; i++) wkc[i] = kCw[i];
  #pragma unroll
  for (int i = 0; i < 27; i++) wkd[i] = kdw[i];
  float m[9];
  #pragma unroll
  for (int i = 0; i < 9; i++) m[i] = M[b * 9 + i];
  float pb[3];
  #pragma unroll
  for (int c = 0; c < 3; c++) pb[c] = proj_b[c];

  const float* xb = x + (size_t)b * NPIX * 3;
  const int row0 = tileY * TY;

  for (int l = tid; l < NHALO; l += 256) {
    int hy = l / HX;
    int hx = l - hy * HX;
    int gy = row0 + hy - 1;
    int gx = tileX * TX + hx - 1;
    float x0 = 0.f, x1 = 0.f, x2 = 0.f;
    if ((unsigned)gy < H && (unsigned)gx < W) {
      const float* xp = xb + (size_t)(gy * W + gx) * 3;
      x0 = xp[0]; x1 = xp[1]; x2 = xp[2];
    }
    km[0][hy][hx] = wkc[0]*x0 + wkc[1]*x1 + wkc[2]*x2;
    km[1][hy][hx] = wkc[3]*x0 + wkc[4]*x1 + wkc[5]*x2;
    km[2][hy][hx] = wkc[6]*x0 + wkc[7]*x1 + wkc[8]*x2;
  }
  __syncthreads();

  const int tx = tid & 15;
  const int ty = tid >> 4;

  float kv[3][4];
  #pragma unroll
  for (int c = 0; c < 3; ++c) {
    #pragma unroll
    for (int i = 0; i < 4; ++i) kv[c][i] = 0.f;
    #pragma unroll
    for (int dy = 0; dy < 3; ++dy) {
      const float4 c0v = *(const float4*)&km[c][ty + dy][4 * tx];
      const float4 c1v = *(const float4*)&km[c][ty + dy][4 * tx + 4];
      const float k0 = wkd[c*9 + dy*3 + 0], k1 = wkd[c*9 + dy*3 + 1], k2 = wkd[c*9 + dy*3 + 2];
      kv[c][0] += k0*c0v.x + k1*c0v.y + k2*c0v.z;
      kv[c][1] += k0*c0v.y + k1*c0v.z + k2*c0v.w;
      kv[c][2] += k0*c0v.z + k1*c0v.w + k2*c1v.x;
      kv[c][3] += k0*c0v.w + k1*c1v.x + k2*c1v.y;
    }
  }

  float o[4][3];
  #pragma unroll
  for (int i = 0; i < 4; ++i) {
    #pragma unroll
    for (int oc = 0; oc < 3; ++oc)
      o[i][oc] = m[oc*3+0]*kv[0][i] + m[oc*3+1]*kv[1][i] + m[oc*3+2]*kv[2][i] + pb[oc];
  }

  const int p0 = (row0 + ty) * W + tileX * TX + 4 * tx;
  float* op = out + ((size_t)b * NPIX + p0) * 3;
  float4 w0, w1, w2;
  w0.x = o[0][0]; w0.y = o[0][1]; w0.z = o[0][2]; w0.w = o[1][0];
  w1.x = o[1][1]; w1.y = o[1][2]; w1.z = o[2][0]; w1.w = o[2][1];
  w2.x = o[2][2]; w2.y = o[3][0]; w2.z = o[3][1]; w2.w = o[3][2];
  *(float4*)(op)     = w0;
  *(float4*)(op + 4) = w1;
  *(float4*)(op + 8) = w2;
}

extern "C" void kernel_launch(void* const* d_in, const int* in_sizes, int n_in,
                              void* d_out, int out_size, void* d_ws, size_t ws_size,
                              hipStream_t stream) {
  const float* x     = (const float*)d_in[0];
  const float* fhigh = (const float*)d_in[1];
  const float* qCw   = (const float*)d_in[2];
  const float* qdw   = (const float*)d_in[3];
  const float* kCw   = (const float*)d_in[4];
  const float* kdw   = (const float*)d_in[5];
  const float* pw    = (const float*)d_in[6];
  const float* pb    = (const float*)d_in[7];
  const float* temp  = (const float*)d_in[8];
  float* out = (float*)d_out;

  float* partials = (float*)d_ws;
  float* M = partials + PART_FLOATS;

  hipMemsetAsync(partials, 0, PART_FLOATS * sizeof(float), stream);

  dim3 grid1(W / TX, H / (TY * NT), BATCH);   // 16 x 16 x 4
  pass1<<<grid1, 256, 0, stream>>>(x, fhigh, qCw, qdw, kCw, kdw, partials);
  pass2<<<1, 64, 0, stream>>>(partials, pw, temp, M);
  dim3 grid3(W / TX, H / TY, BATCH);          // 16 x 64 x 4
  pass3<<<grid3, 256, 0, stream>>>(x, kCw, kdw, M, pb, out);
}